// Round 16
// baseline (6602.673 us; speedup 1.0000x reference)
//
#include <hip/hip_runtime.h>
#include <math.h>

#define BB 16
#define LL 64
#define TT 63          // L-1 steps
#define HH 512
#define AA 32          // ATTN window
#define VV 32000
#define NCHUNK 125     // V chunks (256 cols each)
#define CHW 256
#define TGRP 3         // t-values per mega block (63 = 21*3)
#define NTG 21         // t-groups
#define PAD_TOK 1
#define SOS_TOK 2
#define HSROW 96       // A + L rows in hs_buf
#define ZK 1536        // z length
#define FLTMAX 3.402823466e38f

__device__ __forceinline__ float sigm(float x){ return 1.0f/(1.0f + __expf(-x)); }

// ---------------- prologue: xwpre[t][b][:] = b_ctx + emb[tok(t,b)] @ W_ctx[0:512] ----------------
__global__ __launch_bounds__(256) void k_pre(const int* __restrict__ s, const float* __restrict__ emb,
                      const float* __restrict__ Wctx, const float* __restrict__ bctx,
                      float* __restrict__ xwpre)
{
    int t = blockIdx.x >> 3;          // 0..62
    int jc = blockIdx.x & 7;          // 0..7
    int tid = threadIdx.x;
    int jj = tid & 63, bq = tid >> 6; // bq 0..3
    int j = jc*64 + jj;
    __shared__ int toks[BB];
    __shared__ float xs[BB][HH];
    if (tid < BB) {
        int b = tid;
        toks[b] = (t == 0) ? SOS_TOK : s[b*LL + (t-1)];
    }
    __syncthreads();
    for (int i = tid; i < BB*HH; i += 256) {
        int b = i >> 9, k = i & 511;
        xs[b][k] = emb[(size_t)toks[b]*HH + k];
    }
    __syncthreads();
    float acc[4];
    #pragma unroll
    for (int u = 0; u < 4; u++) acc[u] = bctx[j];
    for (int k = 0; k < HH; k += 4) {
        float w0 = Wctx[(k+0)*HH+j], w1 = Wctx[(k+1)*HH+j],
              w2 = Wctx[(k+2)*HH+j], w3 = Wctx[(k+3)*HH+j];
        #pragma unroll
        for (int u = 0; u < 4; u++) {
            int b = bq*4 + u;
            float4 hv = *reinterpret_cast<const float4*>(&xs[b][k]);
            acc[u] = fmaf(hv.x, w0, acc[u]);
            acc[u] = fmaf(hv.y, w1, acc[u]);
            acc[u] = fmaf(hv.z, w2, acc[u]);
            acc[u] = fmaf(hv.w, w3, acc[u]);
        }
    }
    #pragma unroll
    for (int u = 0; u < 4; u++) {
        int b = bq*4 + u;
        xwpre[((size_t)t*BB + b)*HH + j] = acc[u];
    }
}

// ---------------- one-time: W_glob -> column-blocked k4-major float4 layout (64-col panels) ----
__global__ __launch_bounds__(256) void k_tw(const float* __restrict__ Wg, float4* __restrict__ Wt4b)
{
    int kg = blockIdx.x / 125;            // 0..383
    int cb = blockIdx.x % 125;            // 0..124
    int col = cb*256 + threadIdx.x;
    const float* w0 = Wg + (size_t)(4*kg)*VV + col;
    float4 v;
    v.x = w0[0];
    v.y = w0[VV];
    v.z = w0[2*VV];
    v.w = w0[3*VV];
    Wt4b[(size_t)(col >> 6)*(384*64) + kg*64 + (col & 63)] = v;
}

// ---------------- one-time: W_ih / W_hh (512 x 2048) -> k4-major float4 ----------------
__global__ __launch_bounds__(256) void k_twl(const float* __restrict__ W, float4* __restrict__ WT)
{
    int kg = blockIdx.x >> 3;             // 0..127
    int cb = blockIdx.x & 7;              // 0..7
    int col = cb*256 + threadIdx.x;
    const float* w0 = W + (size_t)(4*kg)*2048 + col;
    float4 v;
    v.x = w0[0];
    v.y = w0[2048];
    v.z = w0[2*2048];
    v.w = w0[3*2048];
    WT[(size_t)kg*2048 + col] = v;
}

// ---------------- step-finish: replicate fp32 log_softmax + s*logp quantization ----------------
// (bit-identical to rounds 2-15; NCHUNK=125 guard — gmax is a pure max, grouping-safe)
__device__ void finish_step(int tp, int b, int tid,
                            const int* __restrict__ s,
                            const float* __restrict__ lb,
                            const float* __restrict__ pmax,
                            const float* __restrict__ spart,
                            const float* __restrict__ bsw,
                            float* __restrict__ nll, float* __restrict__ out,
                            float* cv, int* ci, double* sdd, float* extra)
{
    float v = -FLTMAX;
    if (tid < NCHUNK) v = pmax[tid*BB + b];
    cv[tid] = v; __syncthreads();
    for (int sft = 256; sft >= 1; sft >>= 1) {
        if (tid < sft) cv[tid] = fmaxf(cv[tid], cv[tid+sft]);
        __syncthreads();
    }
    float gmax = cv[0];
    __syncthreads();

    const float* Lb = lb + (size_t)b*VV;
    double sd = 0.0;
    for (int col = tid; col < VV; col += 512) {
        float d1 = Lb[col] - gmax;
        double u = (double)d1, e;
        if (u < -0.25) {
            e = exp(u);
        } else {
            e = 1.0 + u*(1.0/7.0);
            e = 1.0 + u*e*(1.0/6.0);
            e = 1.0 + u*e*(1.0/5.0);
            e = 1.0 + u*e*(1.0/4.0);
            e = 1.0 + u*e*(1.0/3.0);
            e = 1.0 + u*e*(1.0/2.0);
            e = 1.0 + u*e;
        }
        sd += e;
    }
    sdd[tid] = sd; __syncthreads();
    for (int sft = 256; sft >= 1; sft >>= 1) {
        if (tid < sft) sdd[tid] += sdd[tid+sft];
        __syncthreads();
    }
    float logS = logf((float)sdd[0]);

    float z = bsw[0];
    #pragma unroll
    for (int i2 = 0; i2 < 8; i2++) z += spart[b*8 + i2];
    float sF = 1.0f/(1.0f + expf(-z));
    __syncthreads();

    int tg = s[b*LL + tp + 1];
    float best = -FLTMAX; int bidx = 0x7fffffff;
    for (int col = tid; col < VV; col += 512) {
        float d1 = Lb[col] - gmax;
        float d2 = d1 - logS;
        float pq = sF * d2;
        if (pq > best) { best = pq; bidx = col; }
        if (col == tg) extra[0] = pq;
    }
    cv[tid] = best; ci[tid] = bidx; __syncthreads();
    for (int sft = 256; sft >= 1; sft >>= 1) {
        if (tid < sft) {
            float v2 = cv[tid+sft]; int i2 = ci[tid+sft];
            if (v2 > cv[tid] || (v2 == cv[tid] && i2 < ci[tid])) { cv[tid] = v2; ci[tid] = i2; }
        }
        __syncthreads();
    }
    if (tid == 0) {
        out[1 + b*TT + tp] = (float)ci[0];
        nll[tp*BB + b] = (tg != PAD_TOK) ? -extra[0] : 0.f;
    }
    __syncthreads();
}

// ---------------- deferred finishes ----------------
__global__ __launch_bounds__(512) void k_fin_all(
    int t0, const int* __restrict__ s,
    const float* __restrict__ lbBase, unsigned long long lbStride,
    const float* __restrict__ pmaxBase, unsigned long long pmaxStride,
    const float* __restrict__ spartAll, const float* __restrict__ bsw,
    float* __restrict__ nll, float* __restrict__ out)
{
    __shared__ float cv[512];
    __shared__ int   ci[512];
    __shared__ double sdd[512];
    __shared__ float extra[2];
    int idx = blockIdx.x >> 4;
    int tp = t0 + idx, b = blockIdx.x & 15;
    finish_step(tp, b, threadIdx.x, s,
                lbBase + (size_t)idx * lbStride,
                pmaxBase + (size_t)idx * pmaxStride,
                spartAll + (size_t)tp * 128,
                bsw, nll, out, cv, ci, sdd, extra);
}

// ---------------- per-step kernel 1: attention + hid (r11 verbatim, 16 blocks x 512) ----------------
__global__ __launch_bounds__(512) void k_attn(
    int t,
    const float* __restrict__ Whid, const float* __restrict__ bhid,
    const float* __restrict__ vw, const float* __restrict__ vb,
    const float* __restrict__ Wctx, const float* __restrict__ xwpre,
    const float* __restrict__ hs, float* __restrict__ hidg)
{
    int b = blockIdx.x, tid = threadIdx.x;
    __shared__ float hsh[HH], qs[HH], ctxs[HH];
    __shared__ float sc[AA], at[AA];
    const float* hp = hs + ((size_t)b*HSROW + (AA + t - 1))*HH;
    hsh[tid] = hp[tid];
    __syncthreads();
    {
        int j = tid;
        float acc = bhid[j];
        for (int k = 0; k < HH; k += 4) {
            float4 hv = *reinterpret_cast<const float4*>(&hsh[k]);
            acc = fmaf(hv.x, Whid[(k+0)*HH+j], acc);
            acc = fmaf(hv.y, Whid[(k+1)*HH+j], acc);
            acc = fmaf(hv.z, Whid[(k+2)*HH+j], acc);
            acc = fmaf(hv.w, Whid[(k+3)*HH+j], acc);
        }
        qs[j] = acc;
    }
    __syncthreads();
    {
        int w = tid >> 6, lane = tid & 63;
        for (int r = 0; r < 4; r++) {
            int a = w + 8*r;
            const float* mem = hs + ((size_t)b*HSROW + (t + a))*HH;
            float p = 0.f;
            for (int j = lane; j < HH; j += 64) p += tanhf(qs[j] + mem[j]) * vw[j];
            for (int m = 32; m >= 1; m >>= 1) p += __shfl_xor(p, m);
            if (lane == 0) sc[a] = (a >= AA - t) ? (p + vb[0]) : -1e20f;
        }
    }
    __syncthreads();
    if (tid < 64) {
        float v = (tid < 32) ? sc[tid] : -FLTMAX;
        float m = v;
        for (int sh = 16; sh >= 1; sh >>= 1) m = fmaxf(m, __shfl_xor(m, sh));
        float e = (tid < 32) ? __expf(v - m) : 0.f;
        float ss = e;
        for (int sh = 16; sh >= 1; sh >>= 1) ss += __shfl_xor(ss, sh);
        if (tid < 32) at[tid] = e / ss;
    }
    __syncthreads();
    {
        int j = tid;
        float ctx = 0.f;
        for (int a = 0; a < AA; a++)
            ctx += at[a] * hs[((size_t)b*HSROW + (t + a))*HH + j];
        ctxs[j] = ctx;
    }
    __syncthreads();
    {
        int j = tid;
        float acc = xwpre[((size_t)t*BB + b)*HH + j];
        const float* W2 = Wctx + (size_t)HH*HH;
        for (int k = 0; k < HH; k += 4) {
            float4 hv = *reinterpret_cast<const float4*>(&ctxs[k]);
            acc = fmaf(hv.x, W2[(k+0)*HH+j], acc);
            acc = fmaf(hv.y, W2[(k+1)*HH+j], acc);
            acc = fmaf(hv.z, W2[(k+2)*HH+j], acc);
            acc = fmaf(hv.w, W2[(k+3)*HH+j], acc);
        }
        const float scl = 1.0507009873554805f, al = 1.6732632423543772f;
        hidg[b*HH + j] = (acc > 0.f) ? scl*acc : scl*al*expm1f(acc);
    }
}

// ---------------- per-step kernel 2: gates (r11 verbatim, 128 blocks x 256) ----------------
__global__ __launch_bounds__(256) void k_gates(
    int t, const int* __restrict__ parents,
    const float4* __restrict__ WihT, const float4* __restrict__ WhhT,
    const float* __restrict__ blstm, const float* __restrict__ wsw,
    const float* __restrict__ hidg, float* __restrict__ hs,
    float* __restrict__ cvec, float* __restrict__ spart,
    float* __restrict__ zbuf)
{
    int bid = blockIdx.x, b = bid >> 3, hc = bid & 7, h0 = hc*64;
    int tid = threadIdx.x, g = tid >> 6, jj = tid & 63, j = h0 + jj, col = g*HH + j;
    __shared__ float hid_s[HH], h_s[HH];
    __shared__ float gsl[4][64];
    const float* hp = hs + ((size_t)b*HSROW + (AA + t - 1))*HH;
    for (int k = tid; k < HH; k += 256) { hid_s[k] = hidg[b*HH + k]; h_s[k] = hp[k]; }
    __syncthreads();
    float acc = blstm[col];
    #pragma unroll 8
    for (int kg = 0; kg < 128; kg++) {
        float4 w = WihT[(size_t)kg*2048 + col];
        float4 hv = *reinterpret_cast<const float4*>(&hid_s[kg*4]);
        acc = fmaf(hv.x, w.x, acc);
        acc = fmaf(hv.y, w.y, acc);
        acc = fmaf(hv.z, w.z, acc);
        acc = fmaf(hv.w, w.w, acc);
    }
    #pragma unroll 8
    for (int kg = 0; kg < 128; kg++) {
        float4 w = WhhT[(size_t)kg*2048 + col];
        float4 hv = *reinterpret_cast<const float4*>(&h_s[kg*4]);
        acc = fmaf(hv.x, w.x, acc);
        acc = fmaf(hv.y, w.y, acc);
        acc = fmaf(hv.z, w.z, acc);
        acc = fmaf(hv.w, w.w, acc);
    }
    gsl[g][jj] = acc;
    __syncthreads();
    if (tid >= 64 && tid < 128) {
        int jj2 = tid - 64;
        int par = parents[t];
        int tm1 = (t - 1 > 0) ? (t - 1) : 0;
        int p = (par < 0) ? 0 : ((par > tm1) ? tm1 : par);
        float v = (t == 0) ? 0.f : hs[((size_t)b*HSROW + (AA + p))*HH + h0 + jj2];
        zbuf[(size_t)b*ZK + 2*HH + h0 + jj2] = v;
    }
    if (tid < 64) {
        float gi = gsl[0][jj], gf = gsl[1][jj], gg = gsl[2][jj], go = gsl[3][jj];
        float cp = cvec[b*HH + j];
        float cn = sigm(gf)*cp + sigm(gi)*tanhf(gg);
        float hn = sigm(go)*tanhf(cn);
        cvec[b*HH + j] = cn;
        hs[((size_t)b*HSROW + (AA + t))*HH + j] = hn;
        zbuf[(size_t)b*ZK + j] = hn;
        zbuf[(size_t)b*ZK + HH + j] = cn;
        float sp = hn*wsw[j] + cn*wsw[HH + j];
        for (int m = 32; m >= 1; m >>= 1) sp += __shfl_xor(sp, m);
        if (jj == 0) spart[b*8 + hc] = sp;
    }
}

// ---------------- logits GEMM body v5: LDS-staged z + 8 cols/thread (256-col chunks) ----------
// 256 thr: lane=tid&63, cg=lane&31, kh=lane>>5, b0=(tid>>6)*4. Thread: 8 cols x 4 b x NT t.
// Per-(col,b,kh) fmaf chains (kc asc, sub asc, kl asc, z.x..z.w nesting), shfl_xor(32)
// accA+accB combine, lb stores: bit-identical to rounds 2-15. pmax = pure max.
template<int NT>
__device__ __forceinline__ void logits_body5(int chunk, int base_t,
    const float4* __restrict__ Wt4b, const float* __restrict__ bg,
    const float* __restrict__ zBase, size_t zStride,
    float* __restrict__ lbBase, size_t lbStride,
    float* __restrict__ pmaxBase, size_t pmaxStride,
    float* zs)   // NT*16*2*64 floats
{
    int tid = threadIdx.x;
    int lane = tid & 63;
    int cg = lane & 31;
    int kh = lane >> 5;
    int b0 = (tid >> 6) * 4;

    const float4* wt[8];
    #pragma unroll
    for (int cc = 0; cc < 8; cc++)
        wt[cc] = Wt4b + (size_t)(chunk*4 + (cc >> 1))*(384*64) + cg + 32*(cc & 1);

    float acc[NT][8][4];
    #pragma unroll
    for (int tt = 0; tt < NT; tt++)
        #pragma unroll
        for (int cc = 0; cc < 8; cc++) {
            float binit = (kh == 0) ? bg[chunk*CHW + cg + 32*cc] : 0.f;
            #pragma unroll
            for (int u = 0; u < 4; u++) acc[tt][cc][u] = binit;
        }

    const int NF4 = NT*16*2*16;          // float4 slots per sub-chunk
    for (int kc = 0; kc < 3; kc++) {
        for (int sub = 0; sub < 4; sub++) {
            __syncthreads();             // zs free to overwrite
            for (int p = 0; p < NF4/256; p++) {
                int fi = tid + p*256;
                int kl4 = fi & 15;
                int khs = (fi >> 4) & 1;
                int u   = (fi >> 5) & 15;
                int tt  = fi >> 9;
                const float* src = zBase + (size_t)(base_t + tt)*zStride + kc*512
                                 + (size_t)u*ZK + khs*256 + sub*64 + kl4*4;
                *reinterpret_cast<float4*>(&zs[(((tt*16 + u)*2 + khs)*64) + kl4*4]) =
                    *reinterpret_cast<const float4*>(src);
            }
            __syncthreads();
            int kgb = kc*128 + kh*64 + sub*16;
            #pragma unroll 2
            for (int kl = 0; kl < 16; kl++) {
                size_t wof = (size_t)(kgb + kl)*64;
                float4 w[8];
                #pragma unroll
                for (int cc = 0; cc < 8; cc++) w[cc] = wt[cc][wof];
                #pragma unroll
                for (int tt = 0; tt < NT; tt++) {
                    #pragma unroll
                    for (int u = 0; u < 4; u++) {
                        float4 z = *reinterpret_cast<const float4*>(
                            &zs[(((tt*16 + (b0 + u))*2 + kh)*64) + kl*4]);
                        #pragma unroll
                        for (int cc = 0; cc < 8; cc++)
                            acc[tt][cc][u] = fmaf(z.x, w[cc].x, fmaf(z.y, w[cc].y,
                                              fmaf(z.z, w[cc].z, fmaf(z.w, w[cc].w, acc[tt][cc][u]))));
                    }
                }
            }
        }
    }

    #pragma unroll
    for (int tt = 0; tt < NT; tt++) {
        float* lb   = lbBase   + (size_t)(base_t + tt)*lbStride;
        float* pmax = pmaxBase + (size_t)(base_t + tt)*pmaxStride;
        #pragma unroll
        for (int u = 0; u < 4; u++) {
            float vmax = -FLTMAX;
            #pragma unroll
            for (int cc = 0; cc < 8; cc++) {
                float a = acc[tt][cc][u];
                float oth = __shfl_xor(a, 32);
                float tot = a + oth;          // accA+accB (identical bits both halves)
                if (kh == 0) lb[(size_t)(b0 + u)*VV + chunk*CHW + cg + 32*cc] = tot;
                vmax = fmaxf(vmax, tot);
            }
            for (int m = 16; m >= 1; m >>= 1) vmax = fmaxf(vmax, __shfl_xor(vmax, m));
            if (lane == 0) pmax[chunk*BB + b0 + u] = vmax;
        }
    }
}

// mega: grid (21, 125)
__global__ __launch_bounds__(256) void k_logits_mega3(
    const float4* __restrict__ Wt4b, const float* __restrict__ bg,
    const float* __restrict__ zBase,
    float* __restrict__ lbBase, float* __restrict__ pmaxBase)
{
    __shared__ float zs[TGRP*16*2*64];
    logits_body5<TGRP>(blockIdx.y, blockIdx.x * TGRP, Wt4b, bg,
                       zBase, (size_t)BB*ZK, lbBase, 512000, pmaxBase, 2000, zs);
}

// per-step fallback (transposed): grid (125)
__global__ __launch_bounds__(256) void k_logits_T1(
    const float4* __restrict__ Wt4b, const float* __restrict__ bg,
    const float* __restrict__ zbuf,
    float* __restrict__ lb, float* __restrict__ pmax)
{
    __shared__ float zs[1*16*2*64];
    logits_body5<1>(blockIdx.x, 0, Wt4b, bg, zbuf, 0, lb, 0, pmax, 0, zs);
}

// ---------------- fallback untransposed logits (mode 0), grid (125), 256-col chunks ----------------
__global__ __launch_bounds__(256) void k_logits_F(
    const float* __restrict__ Wg, const float* __restrict__ bg,
    const float* __restrict__ zbuf,
    float* __restrict__ lb, float* __restrict__ pmax)
{
    int tid = threadIdx.x;
    int chunk = blockIdx.x;
    int lane = tid & 63;
    int cg = lane & 31;
    int kh = lane >> 5;
    int b0 = (tid >> 6) * 4;

    float acc[8][4];
    #pragma unroll
    for (int cc = 0; cc < 8; cc++) {
        float binit = (kh == 0) ? bg[chunk*CHW + cg + 32*cc] : 0.f;
        #pragma unroll
        for (int u = 0; u < 4; u++) acc[cc][u] = binit;
    }

    for (int kc = 0; kc < 3; kc++) {
        const float* zb = zbuf + kc*512 + (size_t)b0*ZK;
        #pragma unroll 2
        for (int k4 = 0; k4 < 64; k4++) {
            int kb = kh*256 + k4*4;
            const float* wr = Wg + (size_t)(kc*512 + kb)*VV + chunk*CHW + cg;
            float4 w[8];
            #pragma unroll
            for (int cc = 0; cc < 8; cc++) {
                w[cc].x = wr[32*cc];
                w[cc].y = wr[(size_t)VV + 32*cc];
                w[cc].z = wr[(size_t)2*VV + 32*cc];
                w[cc].w = wr[(size_t)3*VV + 32*cc];
            }
            #pragma unroll
            for (int u = 0; u < 4; u++) {
                float4 z = *reinterpret_cast<const float4*>(&zb[(size_t)u*ZK + kb]);
                #pragma unroll
                for (int cc = 0; cc < 8; cc++)
                    acc[cc][u] = fmaf(z.x, w[cc].x, fmaf(z.y, w[cc].y, fmaf(z.z, w[cc].z, fmaf(z.w, w[cc].w, acc[cc][u]))));
            }
        }
    }

    #pragma unroll
    for (int u = 0; u < 4; u++) {
        float vmax = -FLTMAX;
        #pragma unroll
        for (int cc = 0; cc < 8; cc++) {
            float a = acc[cc][u];
            float oth = __shfl_xor(a, 32);
            float tot = a + oth;
            if (kh == 0) lb[(size_t)(b0 + u)*VV + chunk*CHW + cg + 32*cc] = tot;
            vmax = fmaxf(vmax, tot);
        }
        for (int m = 16; m >= 1; m >>= 1) vmax = fmaxf(vmax, __shfl_xor(vmax, m));
        if (lane == 0) pmax[chunk*BB + b0 + u] = vmax;
    }
}

// ---------------- loss ----------------
__global__ __launch_bounds__(256) void k_final_loss(
    const float* __restrict__ nll, float* __restrict__ out)
{
    __shared__ double cs2[256];
    int tid = threadIdx.x;
    double psm = 0.0;
    for (int i = tid; i < TT*BB; i += 256) psm += (double)nll[i];
    cs2[tid] = psm; __syncthreads();
    for (int sft = 128; sft >= 1; sft >>= 1) {
        if (tid < sft) cs2[tid] += cs2[tid+sft];
        __syncthreads();
    }
    if (tid == 0) out[0] = (float)(cs2[0] / (double)BB);
}

extern "C" void kernel_launch(void* const* d_in, const int* in_sizes, int n_in,
                              void* d_out, int out_size, void* d_ws, size_t ws_size,
                              hipStream_t stream)
{
    const int*   s_tok = (const int*)  d_in[0];
    const int*   par   = (const int*)  d_in[1];
    const float* emb   = (const float*)d_in[2];
    const float* Whid  = (const float*)d_in[3];
    const float* bhid  = (const float*)d_in[4];
    const float* vw    = (const float*)d_in[5];
    const float* vb    = (const float*)d_in[6];
    const float* Wctx  = (const float*)d_in[7];
    const float* bctx  = (const float*)d_in[8];
    const float* Wih   = (const float*)d_in[9];
    const float* Whh   = (const float*)d_in[10];
    const float* blstm = (const float*)d_in[11];
    const float* Wg    = (const float*)d_in[12];
    const float* bg    = (const float*)d_in[13];
    const float* wsw   = (const float*)d_in[14];
    const float* bsw   = (const float*)d_in[15];
    float* out = (float*)d_out;

    size_t ws_f = ws_size / sizeof(float);
    const size_t base_f = 786432 + 8192 + 516096 + 8192;       // hs,cvec,xwpre,hidg
    const size_t com_f  = 8064 + 1008 + 2*1048576;             // spartAll, nll, WihT, WhhT
    const size_t full_f = base_f + com_f + (size_t)63*2000 + (size_t)63*512000
                        + (size_t)63*24576 + 49152000;
    const size_t mid_f  = base_f + com_f + 2000 + 512000 + 24576 + 49152000;
    int mode = (ws_f >= full_f) ? 2 : ((ws_f >= mid_f) ? 1 : 0);

    float* ws = (float*)d_ws;
    size_t off = 0;
    float* hs      = ws + off; off += 786432;
    float* cvec    = ws + off; off += 8192;
    float* xwpre   = ws + off; off += 516096;
    float* hidg    = ws + off; off += 8192;
    float* pmaxAll = ws + off; off += (mode == 2) ? (size_t)63*2000 : 2000;
    float* spartAll= ws + off; off += 8064;
    float* nll     = ws + off; off += 1008;
    float* zbufAll = ws + off; off += (mode == 2) ? (size_t)63*24576 : 24576;
    float* lbAll   = ws + off; off += (mode == 2) ? (size_t)63*512000 : 512000;
    float4* WihT   = (float4*)(ws + off); off += 1048576;
    float4* WhhT   = (float4*)(ws + off); off += 1048576;
    float4* Wt4b   = (float4*)(ws + off); // only used in mode>=1

    hipMemsetAsync(hs, 0, (786432 + 8192) * sizeof(float), stream);

    hipLaunchKernelGGL(k_twl, dim3(1024), dim3(256), 0, stream, Wih, WihT);
    hipLaunchKernelGGL(k_twl, dim3(1024), dim3(256), 0, stream, Whh, WhhT);
    if (mode >= 1) {
        hipLaunchKernelGGL(k_tw, dim3(384*125), dim3(256), 0, stream, Wg, Wt4b);
    }
    hipLaunchKernelGGL(k_pre, dim3(TT*8), dim3(256), 0, stream, s_tok, emb, Wctx, bctx, xwpre);

    if (mode == 2) {
        // 1) recurrence: per-step attn + gates (r11 structure, weights L2-shared)
        for (int t = 0; t < TT; t++) {
            hipLaunchKernelGGL(k_attn, dim3(BB), dim3(512), 0, stream,
                t, Whid, bhid, vw, vb, Wctx, xwpre, hs, hidg);
            hipLaunchKernelGGL(k_gates, dim3(128), dim3(256), 0, stream,
                t, par, WihT, WhhT, blstm, wsw, hidg, hs, cvec,
                spartAll + (size_t)t*128, zbufAll + (size_t)t*BB*ZK);
        }
        // 2) all 63 logits GEMMs in one dispatch, z LDS-staged, 8 cols/thread
        hipLaunchKernelGGL(k_logits_mega3, dim3(NTG, NCHUNK), dim3(256), 0, stream,
            Wt4b, bg, zbufAll, lbAll, pmaxAll);
        // 3) all finishes
        hipLaunchKernelGGL(k_fin_all, dim3(TT*BB), dim3(512), 0, stream,
            0, s_tok, lbAll, (unsigned long long)512000,
            pmaxAll, (unsigned long long)2000,
            spartAll, bsw, nll, out);
    } else {
        for (int t = 0; t < TT; t++) {
            hipLaunchKernelGGL(k_attn, dim3(BB), dim3(512), 0, stream,
                t, Whid, bhid, vw, vb, Wctx, xwpre, hs, hidg);
            hipLaunchKernelGGL(k_gates, dim3(128), dim3(256), 0, stream,
                t, par, WihT, WhhT, blstm, wsw, hidg, hs, cvec,
                spartAll + (size_t)t*128, zbufAll);
            if (mode >= 1) {
                hipLaunchKernelGGL(k_logits_T1, dim3(NCHUNK), dim3(256), 0, stream,
                    Wt4b, bg, zbufAll, lbAll, pmaxAll);
            } else {
                hipLaunchKernelGGL(k_logits_F, dim3(NCHUNK), dim3(256), 0, stream,
                    Wg, bg, zbufAll, lbAll, pmaxAll);
            }
            hipLaunchKernelGGL(k_fin_all, dim3(BB), dim3(512), 0, stream,
                t, s_tok, lbAll, (unsigned long long)0, pmaxAll, (unsigned long long)0,
                spartAll, bsw, nll, out);
        }
    }
    hipLaunchKernelGGL(k_final_loss, dim3(1), dim3(256), 0, stream, nll, out);
}

// Round 17
// 5117.741 us; speedup vs baseline: 1.2902x; 1.2902x over previous
//
#include <hip/hip_runtime.h>
#include <math.h>

#define BB 16
#define LL 64
#define TT 63          // L-1 steps
#define HH 512
#define AA 32          // ATTN window
#define VV 32000
#define NCHUNK 250     // V chunks (128 cols each)
#define CHW 128
#define TGRP 3         // t-values per mega block (63 = 21*3)
#define NTG 21         // t-groups
#define PAD_TOK 1
#define SOS_TOK 2
#define HSROW 96       // A + L rows in hs_buf
#define ZK 1536        // z length
#define FLTMAX 3.402823466e38f

__device__ __forceinline__ float sigm(float x){ return 1.0f/(1.0f + __expf(-x)); }

// ---------------- prologue: xwpre[t][b][:] = b_ctx + emb[tok(t,b)] @ W_ctx[0:512] ----------------
__global__ __launch_bounds__(256) void k_pre(const int* __restrict__ s, const float* __restrict__ emb,
                      const float* __restrict__ Wctx, const float* __restrict__ bctx,
                      float* __restrict__ xwpre)
{
    int t = blockIdx.x >> 3;          // 0..62
    int jc = blockIdx.x & 7;          // 0..7
    int tid = threadIdx.x;
    int jj = tid & 63, bq = tid >> 6; // bq 0..3
    int j = jc*64 + jj;
    __shared__ int toks[BB];
    __shared__ float xs[BB][HH];
    if (tid < BB) {
        int b = tid;
        toks[b] = (t == 0) ? SOS_TOK : s[b*LL + (t-1)];
    }
    __syncthreads();
    for (int i = tid; i < BB*HH; i += 256) {
        int b = i >> 9, k = i & 511;
        xs[b][k] = emb[(size_t)toks[b]*HH + k];
    }
    __syncthreads();
    float acc[4];
    #pragma unroll
    for (int u = 0; u < 4; u++) acc[u] = bctx[j];
    for (int k = 0; k < HH; k += 4) {
        float w0 = Wctx[(k+0)*HH+j], w1 = Wctx[(k+1)*HH+j],
              w2 = Wctx[(k+2)*HH+j], w3 = Wctx[(k+3)*HH+j];
        #pragma unroll
        for (int u = 0; u < 4; u++) {
            int b = bq*4 + u;
            float4 hv = *reinterpret_cast<const float4*>(&xs[b][k]);
            acc[u] = fmaf(hv.x, w0, acc[u]);
            acc[u] = fmaf(hv.y, w1, acc[u]);
            acc[u] = fmaf(hv.z, w2, acc[u]);
            acc[u] = fmaf(hv.w, w3, acc[u]);
        }
    }
    #pragma unroll
    for (int u = 0; u < 4; u++) {
        int b = bq*4 + u;
        xwpre[((size_t)t*BB + b)*HH + j] = acc[u];
    }
}

// ---------------- one-time: W_glob -> column-blocked k4-major float4 layout ----------------
__global__ __launch_bounds__(256) void k_tw(const float* __restrict__ Wg, float4* __restrict__ Wt4b)
{
    int kg = blockIdx.x / 125;            // 0..383
    int cb = blockIdx.x % 125;            // 0..124
    int col = cb*256 + threadIdx.x;
    const float* w0 = Wg + (size_t)(4*kg)*VV + col;
    float4 v;
    v.x = w0[0];
    v.y = w0[VV];
    v.z = w0[2*VV];
    v.w = w0[3*VV];
    Wt4b[(size_t)(col >> 6)*(384*64) + kg*64 + (col & 63)] = v;
}

// ---------------- one-time: W_ih / W_hh (512 x 2048) -> k4-major float4 ----------------
__global__ __launch_bounds__(256) void k_twl(const float* __restrict__ W, float4* __restrict__ WT)
{
    int kg = blockIdx.x >> 3;             // 0..127
    int cb = blockIdx.x & 7;              // 0..7
    int col = cb*256 + threadIdx.x;
    const float* w0 = W + (size_t)(4*kg)*2048 + col;
    float4 v;
    v.x = w0[0];
    v.y = w0[2048];
    v.z = w0[2*2048];
    v.w = w0[3*2048];
    WT[(size_t)kg*2048 + col] = v;
}

// ---------------- step-finish: replicate fp32 log_softmax + s*logp quantization ----------------
// (bit-identical to rounds 2-15)
__device__ void finish_step(int tp, int b, int tid,
                            const int* __restrict__ s,
                            const float* __restrict__ lb,
                            const float* __restrict__ pmax,
                            const float* __restrict__ spart,
                            const float* __restrict__ bsw,
                            float* __restrict__ nll, float* __restrict__ out,
                            float* cv, int* ci, double* sdd, float* extra)
{
    float v = -FLTMAX;
    if (tid < NCHUNK) v = pmax[tid*BB + b];
    cv[tid] = v; __syncthreads();
    for (int sft = 256; sft >= 1; sft >>= 1) {
        if (tid < sft) cv[tid] = fmaxf(cv[tid], cv[tid+sft]);
        __syncthreads();
    }
    float gmax = cv[0];
    __syncthreads();

    const float* Lb = lb + (size_t)b*VV;
    double sd = 0.0;
    for (int col = tid; col < VV; col += 512) {
        float d1 = Lb[col] - gmax;
        double u = (double)d1, e;
        if (u < -0.25) {
            e = exp(u);
        } else {
            e = 1.0 + u*(1.0/7.0);
            e = 1.0 + u*e*(1.0/6.0);
            e = 1.0 + u*e*(1.0/5.0);
            e = 1.0 + u*e*(1.0/4.0);
            e = 1.0 + u*e*(1.0/3.0);
            e = 1.0 + u*e*(1.0/2.0);
            e = 1.0 + u*e;
        }
        sd += e;
    }
    sdd[tid] = sd; __syncthreads();
    for (int sft = 256; sft >= 1; sft >>= 1) {
        if (tid < sft) sdd[tid] += sdd[tid+sft];
        __syncthreads();
    }
    float logS = logf((float)sdd[0]);

    float z = bsw[0];
    #pragma unroll
    for (int i2 = 0; i2 < 8; i2++) z += spart[b*8 + i2];
    float sF = 1.0f/(1.0f + expf(-z));
    __syncthreads();

    int tg = s[b*LL + tp + 1];
    float best = -FLTMAX; int bidx = 0x7fffffff;
    for (int col = tid; col < VV; col += 512) {
        float d1 = Lb[col] - gmax;
        float d2 = d1 - logS;
        float pq = sF * d2;
        if (pq > best) { best = pq; bidx = col; }
        if (col == tg) extra[0] = pq;
    }
    cv[tid] = best; ci[tid] = bidx; __syncthreads();
    for (int sft = 256; sft >= 1; sft >>= 1) {
        if (tid < sft) {
            float v2 = cv[tid+sft]; int i2 = ci[tid+sft];
            if (v2 > cv[tid] || (v2 == cv[tid] && i2 < ci[tid])) { cv[tid] = v2; ci[tid] = i2; }
        }
        __syncthreads();
    }
    if (tid == 0) {
        out[1 + b*TT + tp] = (float)ci[0];
        nll[tp*BB + b] = (tg != PAD_TOK) ? -extra[0] : 0.f;
    }
    __syncthreads();
}

// ---------------- deferred finishes ----------------
__global__ __launch_bounds__(512) void k_fin_all(
    int t0, const int* __restrict__ s,
    const float* __restrict__ lbBase, unsigned long long lbStride,
    const float* __restrict__ pmaxBase, unsigned long long pmaxStride,
    const float* __restrict__ spartAll, const float* __restrict__ bsw,
    float* __restrict__ nll, float* __restrict__ out)
{
    __shared__ float cv[512];
    __shared__ int   ci[512];
    __shared__ double sdd[512];
    __shared__ float extra[2];
    int idx = blockIdx.x >> 4;
    int tp = t0 + idx, b = blockIdx.x & 15;
    finish_step(tp, b, threadIdx.x, s,
                lbBase + (size_t)idx * lbStride,
                pmaxBase + (size_t)idx * pmaxStride,
                spartAll + (size_t)tp * 128,
                bsw, nll, out, cv, ci, sdd, extra);
}

// ---------------- per-step kernel 1: attention + hid (r11 verbatim, 16 blocks x 512) ----------------
__global__ __launch_bounds__(512) void k_attn(
    int t,
    const float* __restrict__ Whid, const float* __restrict__ bhid,
    const float* __restrict__ vw, const float* __restrict__ vb,
    const float* __restrict__ Wctx, const float* __restrict__ xwpre,
    const float* __restrict__ hs, float* __restrict__ hidg)
{
    int b = blockIdx.x, tid = threadIdx.x;
    __shared__ float hsh[HH], qs[HH], ctxs[HH];
    __shared__ float sc[AA], at[AA];
    const float* hp = hs + ((size_t)b*HSROW + (AA + t - 1))*HH;
    hsh[tid] = hp[tid];
    __syncthreads();
    {
        int j = tid;
        float acc = bhid[j];
        for (int k = 0; k < HH; k += 4) {
            float4 hv = *reinterpret_cast<const float4*>(&hsh[k]);
            acc = fmaf(hv.x, Whid[(k+0)*HH+j], acc);
            acc = fmaf(hv.y, Whid[(k+1)*HH+j], acc);
            acc = fmaf(hv.z, Whid[(k+2)*HH+j], acc);
            acc = fmaf(hv.w, Whid[(k+3)*HH+j], acc);
        }
        qs[j] = acc;
    }
    __syncthreads();
    {
        int w = tid >> 6, lane = tid & 63;
        for (int r = 0; r < 4; r++) {
            int a = w + 8*r;
            const float* mem = hs + ((size_t)b*HSROW + (t + a))*HH;
            float p = 0.f;
            for (int j = lane; j < HH; j += 64) p += tanhf(qs[j] + mem[j]) * vw[j];
            for (int m = 32; m >= 1; m >>= 1) p += __shfl_xor(p, m);
            if (lane == 0) sc[a] = (a >= AA - t) ? (p + vb[0]) : -1e20f;
        }
    }
    __syncthreads();
    if (tid < 64) {
        float v = (tid < 32) ? sc[tid] : -FLTMAX;
        float m = v;
        for (int sh = 16; sh >= 1; sh >>= 1) m = fmaxf(m, __shfl_xor(m, sh));
        float e = (tid < 32) ? __expf(v - m) : 0.f;
        float ss = e;
        for (int sh = 16; sh >= 1; sh >>= 1) ss += __shfl_xor(ss, sh);
        if (tid < 32) at[tid] = e / ss;
    }
    __syncthreads();
    {
        int j = tid;
        float ctx = 0.f;
        for (int a = 0; a < AA; a++)
            ctx += at[a] * hs[((size_t)b*HSROW + (t + a))*HH + j];
        ctxs[j] = ctx;
    }
    __syncthreads();
    {
        int j = tid;
        float acc = xwpre[((size_t)t*BB + b)*HH + j];
        const float* W2 = Wctx + (size_t)HH*HH;
        for (int k = 0; k < HH; k += 4) {
            float4 hv = *reinterpret_cast<const float4*>(&ctxs[k]);
            acc = fmaf(hv.x, W2[(k+0)*HH+j], acc);
            acc = fmaf(hv.y, W2[(k+1)*HH+j], acc);
            acc = fmaf(hv.z, W2[(k+2)*HH+j], acc);
            acc = fmaf(hv.w, W2[(k+3)*HH+j], acc);
        }
        const float scl = 1.0507009873554805f, al = 1.6732632423543772f;
        hidg[b*HH + j] = (acc > 0.f) ? scl*acc : scl*al*expm1f(acc);
    }
}

// ---------------- per-step kernel 2: gates (r11 verbatim, 128 blocks x 256) ----------------
__global__ __launch_bounds__(256) void k_gates(
    int t, const int* __restrict__ parents,
    const float4* __restrict__ WihT, const float4* __restrict__ WhhT,
    const float* __restrict__ blstm, const float* __restrict__ wsw,
    const float* __restrict__ hidg, float* __restrict__ hs,
    float* __restrict__ cvec, float* __restrict__ spart,
    float* __restrict__ zbuf)
{
    int bid = blockIdx.x, b = bid >> 3, hc = bid & 7, h0 = hc*64;
    int tid = threadIdx.x, g = tid >> 6, jj = tid & 63, j = h0 + jj, col = g*HH + j;
    __shared__ float hid_s[HH], h_s[HH];
    __shared__ float gsl[4][64];
    const float* hp = hs + ((size_t)b*HSROW + (AA + t - 1))*HH;
    for (int k = tid; k < HH; k += 256) { hid_s[k] = hidg[b*HH + k]; h_s[k] = hp[k]; }
    __syncthreads();
    float acc = blstm[col];
    #pragma unroll 8
    for (int kg = 0; kg < 128; kg++) {
        float4 w = WihT[(size_t)kg*2048 + col];
        float4 hv = *reinterpret_cast<const float4*>(&hid_s[kg*4]);
        acc = fmaf(hv.x, w.x, acc);
        acc = fmaf(hv.y, w.y, acc);
        acc = fmaf(hv.z, w.z, acc);
        acc = fmaf(hv.w, w.w, acc);
    }
    #pragma unroll 8
    for (int kg = 0; kg < 128; kg++) {
        float4 w = WhhT[(size_t)kg*2048 + col];
        float4 hv = *reinterpret_cast<const float4*>(&h_s[kg*4]);
        acc = fmaf(hv.x, w.x, acc);
        acc = fmaf(hv.y, w.y, acc);
        acc = fmaf(hv.z, w.z, acc);
        acc = fmaf(hv.w, w.w, acc);
    }
    gsl[g][jj] = acc;
    __syncthreads();
    if (tid >= 64 && tid < 128) {
        int jj2 = tid - 64;
        int par = parents[t];
        int tm1 = (t - 1 > 0) ? (t - 1) : 0;
        int p = (par < 0) ? 0 : ((par > tm1) ? tm1 : par);
        float v = (t == 0) ? 0.f : hs[((size_t)b*HSROW + (AA + p))*HH + h0 + jj2];
        zbuf[(size_t)b*ZK + 2*HH + h0 + jj2] = v;
    }
    if (tid < 64) {
        float gi = gsl[0][jj], gf = gsl[1][jj], gg = gsl[2][jj], go = gsl[3][jj];
        float cp = cvec[b*HH + j];
        float cn = sigm(gf)*cp + sigm(gi)*tanhf(gg);
        float hn = sigm(go)*tanhf(cn);
        cvec[b*HH + j] = cn;
        hs[((size_t)b*HSROW + (AA + t))*HH + j] = hn;
        zbuf[(size_t)b*ZK + j] = hn;
        zbuf[(size_t)b*ZK + HH + j] = cn;
        float sp = hn*wsw[j] + cn*wsw[HH + j];
        for (int m = 32; m >= 1; m >>= 1) sp += __shfl_xor(sp, m);
        if (jj == 0) spart[b*8 + hc] = sp;
    }
}

// ---------------- logits GEMM body v4b: r15 body + register-prefetch staging (T14) ----------------
// Lane layout and ALL arithmetic chains verbatim r15 (bit-identical); only staging timing changes.
template<int NT>
__device__ __forceinline__ void logits_body4(int chunk, int base_t,
    const float4* __restrict__ Wt4b, const float* __restrict__ bg,
    const float* __restrict__ zBase, size_t zStride,
    float* __restrict__ lbBase, size_t lbStride,
    float* __restrict__ pmaxBase, size_t pmaxStride,
    float* zs)   // NT*16*2*64 floats
{
    int tid = threadIdx.x;
    int lane = tid & 63;
    int cg = lane & 31;
    int kh = lane >> 5;
    int b0 = (tid >> 6) * 4;

    const float4* wt0 = Wt4b + (size_t)(chunk*2 + 0)*(384*64) + cg;
    const float4* wt1 = Wt4b + (size_t)(chunk*2 + 0)*(384*64) + cg + 32;
    const float4* wt2 = Wt4b + (size_t)(chunk*2 + 1)*(384*64) + cg;
    const float4* wt3 = Wt4b + (size_t)(chunk*2 + 1)*(384*64) + cg + 32;

    float acc[NT][4][4];
    #pragma unroll
    for (int tt = 0; tt < NT; tt++)
        #pragma unroll
        for (int cc = 0; cc < 4; cc++) {
            float binit = (kh == 0) ? bg[chunk*CHW + cg + 32*cc] : 0.f;
            #pragma unroll
            for (int u = 0; u < 4; u++) acc[tt][cc][u] = binit;
        }

    constexpr int NP = NT*2;             // float4 prefetch regs per thread (NF4/256)
    float4 pre[NP];
    // per-p decode (compile-time after unroll)
    #define PD(p) int fi##p = tid + (p)*256; \
                  int kl4##p = fi##p & 15; int khs##p = (fi##p >> 4) & 1; \
                  int uu##p = (fi##p >> 5) & 15; int tt##p = fi##p >> 9;
    // load sub-chunk (kc,sub) into pre[]
    auto LD = [&](int kc, int sub) {
        #pragma unroll
        for (int p = 0; p < NP; p++) {
            int fi = tid + p*256;
            int kl4 = fi & 15, khs = (fi >> 4) & 1, uu = (fi >> 5) & 15, tt = fi >> 9;
            const float* src = zBase + (size_t)(base_t + tt)*zStride + kc*512
                             + (size_t)uu*ZK + khs*256 + sub*64 + kl4*4;
            pre[p] = *reinterpret_cast<const float4*>(src);
        }
    };
    LD(0, 0);
    for (int kc = 0; kc < 3; kc++) {
        for (int sub = 0; sub < 4; sub++) {
            __syncthreads();             // previous consumers done
            #pragma unroll
            for (int p = 0; p < NP; p++) {
                int fi = tid + p*256;
                int kl4 = fi & 15, khs = (fi >> 4) & 1, uu = (fi >> 5) & 15, tt = fi >> 9;
                *reinterpret_cast<float4*>(&zs[(((tt*16 + uu)*2 + khs)*64) + kl4*4]) = pre[p];
            }
            __syncthreads();             // zs ready
            {   // issue next sub-chunk's loads (overlap with compute below)
                int nsub = sub + 1, nkc = kc;
                if (nsub == 4) { nsub = 0; nkc++; }
                if (nkc < 3) LD(nkc, nsub);
            }
            int kgb = kc*128 + kh*64 + sub*16;
            const float4* w0P = wt0 + (size_t)kgb*64;
            const float4* w1P = wt1 + (size_t)kgb*64;
            const float4* w2P = wt2 + (size_t)kgb*64;
            const float4* w3P = wt3 + (size_t)kgb*64;
            #pragma unroll 4
            for (int kl = 0; kl < 16; kl++) {
                float4 w0 = w0P[kl*64];
                float4 w1 = w1P[kl*64];
                float4 w2 = w2P[kl*64];
                float4 w3 = w3P[kl*64];
                #pragma unroll
                for (int tt = 0; tt < NT; tt++) {
                    #pragma unroll
                    for (int u = 0; u < 4; u++) {
                        float4 z = *reinterpret_cast<const float4*>(
                            &zs[(((tt*16 + (b0 + u))*2 + kh)*64) + kl*4]);
                        acc[tt][0][u] = fmaf(z.x, w0.x, fmaf(z.y, w0.y, fmaf(z.z, w0.z, fmaf(z.w, w0.w, acc[tt][0][u]))));
                        acc[tt][1][u] = fmaf(z.x, w1.x, fmaf(z.y, w1.y, fmaf(z.z, w1.z, fmaf(z.w, w1.w, acc[tt][1][u]))));
                        acc[tt][2][u] = fmaf(z.x, w2.x, fmaf(z.y, w2.y, fmaf(z.z, w2.z, fmaf(z.w, w2.w, acc[tt][2][u]))));
                        acc[tt][3][u] = fmaf(z.x, w3.x, fmaf(z.y, w3.y, fmaf(z.z, w3.z, fmaf(z.w, w3.w, acc[tt][3][u]))));
                    }
                }
            }
        }
    }

    #pragma unroll
    for (int tt = 0; tt < NT; tt++) {
        float* lb   = lbBase   + (size_t)(base_t + tt)*lbStride;
        float* pmax = pmaxBase + (size_t)(base_t + tt)*pmaxStride;
        #pragma unroll
        for (int u = 0; u < 4; u++) {
            float vmax = -FLTMAX;
            #pragma unroll
            for (int cc = 0; cc < 4; cc++) {
                float a = acc[tt][cc][u];
                float oth = __shfl_xor(a, 32);
                float tot = a + oth;          // accA+accB (identical bits both halves)
                if (kh == 0)
                    __builtin_nontemporal_store(tot, &lb[(size_t)(b0 + u)*VV + chunk*CHW + cg + 32*cc]);
                vmax = fmaxf(vmax, tot);
            }
            for (int m = 16; m >= 1; m >>= 1) vmax = fmaxf(vmax, __shfl_xor(vmax, m));
            if (lane == 0) pmax[chunk*BB + b0 + u] = vmax;
        }
    }
}

// mega: 5376 blocks, XCD-swizzled so each chunk's 21 t-group blocks share one XCD's L2
__global__ __launch_bounds__(256) void k_logits_mega3(
    const float4* __restrict__ Wt4b, const float* __restrict__ bg,
    const float* __restrict__ zBase,
    float* __restrict__ lbBase, float* __restrict__ pmaxBase)
{
    __shared__ float zs[TGRP*16*2*64];
    int h = blockIdx.x;
    int r = h & 7, m = h >> 3;
    int w = r*672 + m;                 // 672 = 21*32 -> chunks never straddle XCDs
    if (w >= NTG*NCHUNK) return;       // 5250
    int chunk = w / NTG;
    int base_t = (w % NTG) * TGRP;
    logits_body4<TGRP>(chunk, base_t, Wt4b, bg,
                       zBase, (size_t)BB*ZK, lbBase, 512000, pmaxBase, 4000, zs);
}

// per-step fallback (transposed): grid (250)
__global__ __launch_bounds__(256) void k_logits_T1(
    const float4* __restrict__ Wt4b, const float* __restrict__ bg,
    const float* __restrict__ zbuf,
    float* __restrict__ lb, float* __restrict__ pmax)
{
    __shared__ float zs[1*16*2*64];
    logits_body4<1>(blockIdx.x, 0, Wt4b, bg, zbuf, 0, lb, 0, pmax, 0, zs);
}

// ---------------- fallback untransposed logits (mode 0), grid (250) ----------------
__global__ __launch_bounds__(256) void k_logits_F(
    const float* __restrict__ Wg, const float* __restrict__ bg,
    const float* __restrict__ zbuf,
    float* __restrict__ lb, float* __restrict__ pmax)
{
    int tid = threadIdx.x;
    int chunk = blockIdx.x;
    int lane = tid & 63;
    int cg = lane & 31;
    int kh = lane >> 5;
    int b0 = (tid >> 6) * 4;

    float acc[4][4];
    #pragma unroll
    for (int cc = 0; cc < 4; cc++) {
        float binit = (kh == 0) ? bg[chunk*CHW + cg + 32*cc] : 0.f;
        #pragma unroll
        for (int u = 0; u < 4; u++) acc[cc][u] = binit;
    }

    for (int kc = 0; kc < 3; kc++) {
        const float* zb = zbuf + kc*512 + (size_t)b0*ZK;
        #pragma unroll 2
        for (int k4 = 0; k4 < 64; k4++) {
            int kb = kh*256 + k4*4;
            const float* wr = Wg + (size_t)(kc*512 + kb)*VV + chunk*CHW + cg;
            float4 w[4];
            #pragma unroll
            for (int cc = 0; cc < 4; cc++) {
                w[cc].x = wr[32*cc];
                w[cc].y = wr[(size_t)VV + 32*cc];
                w[cc].z = wr[(size_t)2*VV + 32*cc];
                w[cc].w = wr[(size_t)3*VV + 32*cc];
            }
            #pragma unroll
            for (int u = 0; u < 4; u++) {
                float4 z = *reinterpret_cast<const float4*>(&zb[(size_t)u*ZK + kb]);
                #pragma unroll
                for (int cc = 0; cc < 4; cc++)
                    acc[cc][u] = fmaf(z.x, w[cc].x, fmaf(z.y, w[cc].y, fmaf(z.z, w[cc].z, fmaf(z.w, w[cc].w, acc[cc][u]))));
            }
        }
    }

    #pragma unroll
    for (int u = 0; u < 4; u++) {
        float vmax = -FLTMAX;
        #pragma unroll
        for (int cc = 0; cc < 4; cc++) {
            float a = acc[cc][u];
            float oth = __shfl_xor(a, 32);
            float tot = a + oth;
            if (kh == 0) lb[(size_t)(b0 + u)*VV + chunk*CHW + cg + 32*cc] = tot;
            vmax = fmaxf(vmax, tot);
        }
        for (int m = 16; m >= 1; m >>= 1) vmax = fmaxf(vmax, __shfl_xor(vmax, m));
        if (lane == 0) pmax[chunk*BB + b0 + u] = vmax;
    }
}

// ---------------- loss ----------------
__global__ __launch_bounds__(256) void k_final_loss(
    const float* __restrict__ nll, float* __restrict__ out)
{
    __shared__ double cs2[256];
    int tid = threadIdx.x;
    double psm = 0.0;
    for (int i = tid; i < TT*BB; i += 256) psm += (double)nll[i];
    cs2[tid] = psm; __syncthreads();
    for (int sft = 128; sft >= 1; sft >>= 1) {
        if (tid < sft) cs2[tid] += cs2[tid+sft];
        __syncthreads();
    }
    if (tid == 0) out[0] = (float)(cs2[0] / (double)BB);
}

extern "C" void kernel_launch(void* const* d_in, const int* in_sizes, int n_in,
                              void* d_out, int out_size, void* d_ws, size_t ws_size,
                              hipStream_t stream)
{
    const int*   s_tok = (const int*)  d_in[0];
    const int*   par   = (const int*)  d_in[1];
    const float* emb   = (const float*)d_in[2];
    const float* Whid  = (const float*)d_in[3];
    const float* bhid  = (const float*)d_in[4];
    const float* vw    = (const float*)d_in[5];
    const float* vb    = (const float*)d_in[6];
    const float* Wctx  = (const float*)d_in[7];
    const float* bctx  = (const float*)d_in[8];
    const float* Wih   = (const float*)d_in[9];
    const float* Whh   = (const float*)d_in[10];
    const float* blstm = (const float*)d_in[11];
    const float* Wg    = (const float*)d_in[12];
    const float* bg    = (const float*)d_in[13];
    const float* wsw   = (const float*)d_in[14];
    const float* bsw   = (const float*)d_in[15];
    float* out = (float*)d_out;

    size_t ws_f = ws_size / sizeof(float);
    const size_t base_f = 786432 + 8192 + 516096 + 8192;       // hs,cvec,xwpre,hidg
    const size_t com_f  = 8064 + 1008 + 2*1048576;             // spartAll, nll, WihT, WhhT
    const size_t full_f = base_f + com_f + (size_t)63*4000 + (size_t)63*512000
                        + (size_t)63*24576 + 49152000;
    const size_t mid_f  = base_f + com_f + 4000 + 512000 + 24576 + 49152000;
    int mode = (ws_f >= full_f) ? 2 : ((ws_f >= mid_f) ? 1 : 0);

    float* ws = (float*)d_ws;
    size_t off = 0;
    float* hs      = ws + off; off += 786432;
    float* cvec    = ws + off; off += 8192;
    float* xwpre   = ws + off; off += 516096;
    float* hidg    = ws + off; off += 8192;
    float* pmaxAll = ws + off; off += (mode == 2) ? (size_t)63*4000 : 4000;
    float* spartAll= ws + off; off += 8064;
    float* nll     = ws + off; off += 1008;
    float* zbufAll = ws + off; off += (mode == 2) ? (size_t)63*24576 : 24576;
    float* lbAll   = ws + off; off += (mode == 2) ? (size_t)63*512000 : 512000;
    float4* WihT   = (float4*)(ws + off); off += 1048576;
    float4* WhhT   = (float4*)(ws + off); off += 1048576;
    float4* Wt4b   = (float4*)(ws + off); // only used in mode>=1

    hipMemsetAsync(hs, 0, (786432 + 8192) * sizeof(float), stream);

    hipLaunchKernelGGL(k_twl, dim3(1024), dim3(256), 0, stream, Wih, WihT);
    hipLaunchKernelGGL(k_twl, dim3(1024), dim3(256), 0, stream, Whh, WhhT);
    if (mode >= 1) {
        hipLaunchKernelGGL(k_tw, dim3(384*125), dim3(256), 0, stream, Wg, Wt4b);
    }
    hipLaunchKernelGGL(k_pre, dim3(TT*8), dim3(256), 0, stream, s_tok, emb, Wctx, bctx, xwpre);

    if (mode == 2) {
        // 1) recurrence: per-step attn + gates (r11 structure, weights L2-shared)
        for (int t = 0; t < TT; t++) {
            hipLaunchKernelGGL(k_attn, dim3(BB), dim3(512), 0, stream,
                t, Whid, bhid, vw, vb, Wctx, xwpre, hs, hidg);
            hipLaunchKernelGGL(k_gates, dim3(128), dim3(256), 0, stream,
                t, par, WihT, WhhT, blstm, wsw, hidg, hs, cvec,
                spartAll + (size_t)t*128, zbufAll + (size_t)t*BB*ZK);
        }
        // 2) all 63 logits GEMMs, XCD-swizzled, z LDS-staged w/ register prefetch
        hipLaunchKernelGGL(k_logits_mega3, dim3(8*672), dim3(256), 0, stream,
            Wt4b, bg, zbufAll, lbAll, pmaxAll);
        // 3) all finishes
        hipLaunchKernelGGL(k_fin_all, dim3(TT*BB), dim3(512), 0, stream,
            0, s_tok, lbAll, (unsigned long long)512000,
            pmaxAll, (unsigned long long)4000,
            spartAll, bsw, nll, out);
    } else {
        for (int t = 0; t < TT; t++) {
            hipLaunchKernelGGL(k_attn, dim3(BB), dim3(512), 0, stream,
                t, Whid, bhid, vw, vb, Wctx, xwpre, hs, hidg);
            hipLaunchKernelGGL(k_gates, dim3(128), dim3(256), 0, stream,
                t, par, WihT, WhhT, blstm, wsw, hidg, hs, cvec,
                spartAll + (size_t)t*128, zbufAll);
            if (mode >= 1) {
                hipLaunchKernelGGL(k_logits_T1, dim3(NCHUNK), dim3(256), 0, stream,
                    Wt4b, bg, zbufAll, lbAll, pmaxAll);
            } else {
                hipLaunchKernelGGL(k_logits_F, dim3(NCHUNK), dim3(256), 0, stream,
                    Wg, bg, zbufAll, lbAll, pmaxAll);
            }
            hipLaunchKernelGGL(k_fin_all, dim3(BB), dim3(512), 0, stream,
                t, s_tok, lbAll, (unsigned long long)0, pmaxAll, (unsigned long long)0,
                spartAll, bsw, nll, out);
        }
    }
    hipLaunchKernelGGL(k_final_loss, dim3(1), dim3(256), 0, stream, nll, out);
}

// Round 18
// 4767.426 us; speedup vs baseline: 1.3850x; 1.0735x over previous
//
#include <hip/hip_runtime.h>
#include <math.h>

#define BB 16
#define LL 64
#define TT 63          // L-1 steps
#define HH 512
#define AA 32          // ATTN window
#define VV 32000
#define NCHUNK 250     // V chunks (128 cols each)
#define CHW 128
#define TGRP 3         // t-values per mega block (63 = 21*3)
#define NTG 21         // t-groups
#define PAD_TOK 1
#define SOS_TOK 2
#define HSROW 96       // A + L rows in hs_buf
#define ZK 1536        // z length
#define FLTMAX 3.402823466e38f

__device__ __forceinline__ float sigm(float x){ return 1.0f/(1.0f + __expf(-x)); }

// ---------------- prologue: xwpre[t][b][:] = b_ctx + emb[tok(t,b)] @ W_ctx[0:512] ----------------
__global__ __launch_bounds__(256) void k_pre(const int* __restrict__ s, const float* __restrict__ emb,
                      const float* __restrict__ Wctx, const float* __restrict__ bctx,
                      float* __restrict__ xwpre)
{
    int t = blockIdx.x >> 3;          // 0..62
    int jc = blockIdx.x & 7;          // 0..7
    int tid = threadIdx.x;
    int jj = tid & 63, bq = tid >> 6; // bq 0..3
    int j = jc*64 + jj;
    __shared__ int toks[BB];
    __shared__ float xs[BB][HH];
    if (tid < BB) {
        int b = tid;
        toks[b] = (t == 0) ? SOS_TOK : s[b*LL + (t-1)];
    }
    __syncthreads();
    for (int i = tid; i < BB*HH; i += 256) {
        int b = i >> 9, k = i & 511;
        xs[b][k] = emb[(size_t)toks[b]*HH + k];
    }
    __syncthreads();
    float acc[4];
    #pragma unroll
    for (int u = 0; u < 4; u++) acc[u] = bctx[j];
    for (int k = 0; k < HH; k += 4) {
        float w0 = Wctx[(k+0)*HH+j], w1 = Wctx[(k+1)*HH+j],
              w2 = Wctx[(k+2)*HH+j], w3 = Wctx[(k+3)*HH+j];
        #pragma unroll
        for (int u = 0; u < 4; u++) {
            int b = bq*4 + u;
            float4 hv = *reinterpret_cast<const float4*>(&xs[b][k]);
            acc[u] = fmaf(hv.x, w0, acc[u]);
            acc[u] = fmaf(hv.y, w1, acc[u]);
            acc[u] = fmaf(hv.z, w2, acc[u]);
            acc[u] = fmaf(hv.w, w3, acc[u]);
        }
    }
    #pragma unroll
    for (int u = 0; u < 4; u++) {
        int b = bq*4 + u;
        xwpre[((size_t)t*BB + b)*HH + j] = acc[u];
    }
}

// ---------------- one-time: W_glob -> column-blocked k4-major float4 layout ----------------
__global__ __launch_bounds__(256) void k_tw(const float* __restrict__ Wg, float4* __restrict__ Wt4b)
{
    int kg = blockIdx.x / 125;            // 0..383
    int cb = blockIdx.x % 125;            // 0..124
    int col = cb*256 + threadIdx.x;
    const float* w0 = Wg + (size_t)(4*kg)*VV + col;
    float4 v;
    v.x = w0[0];
    v.y = w0[VV];
    v.z = w0[2*VV];
    v.w = w0[3*VV];
    Wt4b[(size_t)(col >> 6)*(384*64) + kg*64 + (col & 63)] = v;
}

// ---------------- one-time: W_ih / W_hh (512 x 2048) -> k4-major float4 ----------------
__global__ __launch_bounds__(256) void k_twl(const float* __restrict__ W, float4* __restrict__ WT)
{
    int kg = blockIdx.x >> 3;             // 0..127
    int cb = blockIdx.x & 7;              // 0..7
    int col = cb*256 + threadIdx.x;
    const float* w0 = W + (size_t)(4*kg)*2048 + col;
    float4 v;
    v.x = w0[0];
    v.y = w0[2048];
    v.z = w0[2*2048];
    v.w = w0[3*2048];
    WT[(size_t)kg*2048 + col] = v;
}

// ---------------- step-finish: replicate fp32 log_softmax + s*logp quantization ----------------
// (bit-identical to rounds 2-15)
__device__ void finish_step(int tp, int b, int tid,
                            const int* __restrict__ s,
                            const float* __restrict__ lb,
                            const float* __restrict__ pmax,
                            const float* __restrict__ spart,
                            const float* __restrict__ bsw,
                            float* __restrict__ nll, float* __restrict__ out,
                            float* cv, int* ci, double* sdd, float* extra)
{
    float v = -FLTMAX;
    if (tid < NCHUNK) v = pmax[tid*BB + b];
    cv[tid] = v; __syncthreads();
    for (int sft = 256; sft >= 1; sft >>= 1) {
        if (tid < sft) cv[tid] = fmaxf(cv[tid], cv[tid+sft]);
        __syncthreads();
    }
    float gmax = cv[0];
    __syncthreads();

    const float* Lb = lb + (size_t)b*VV;
    double sd = 0.0;
    for (int col = tid; col < VV; col += 512) {
        float d1 = Lb[col] - gmax;
        double u = (double)d1, e;
        if (u < -0.25) {
            e = exp(u);
        } else {
            e = 1.0 + u*(1.0/7.0);
            e = 1.0 + u*e*(1.0/6.0);
            e = 1.0 + u*e*(1.0/5.0);
            e = 1.0 + u*e*(1.0/4.0);
            e = 1.0 + u*e*(1.0/3.0);
            e = 1.0 + u*e*(1.0/2.0);
            e = 1.0 + u*e;
        }
        sd += e;
    }
    sdd[tid] = sd; __syncthreads();
    for (int sft = 256; sft >= 1; sft >>= 1) {
        if (tid < sft) sdd[tid] += sdd[tid+sft];
        __syncthreads();
    }
    float logS = logf((float)sdd[0]);

    float z = bsw[0];
    #pragma unroll
    for (int i2 = 0; i2 < 8; i2++) z += spart[b*8 + i2];
    float sF = 1.0f/(1.0f + expf(-z));
    __syncthreads();

    int tg = s[b*LL + tp + 1];
    float best = -FLTMAX; int bidx = 0x7fffffff;
    for (int col = tid; col < VV; col += 512) {
        float d1 = Lb[col] - gmax;
        float d2 = d1 - logS;
        float pq = sF * d2;
        if (pq > best) { best = pq; bidx = col; }
        if (col == tg) extra[0] = pq;
    }
    cv[tid] = best; ci[tid] = bidx; __syncthreads();
    for (int sft = 256; sft >= 1; sft >>= 1) {
        if (tid < sft) {
            float v2 = cv[tid+sft]; int i2 = ci[tid+sft];
            if (v2 > cv[tid] || (v2 == cv[tid] && i2 < ci[tid])) { cv[tid] = v2; ci[tid] = i2; }
        }
        __syncthreads();
    }
    if (tid == 0) {
        out[1 + b*TT + tp] = (float)ci[0];
        nll[tp*BB + b] = (tg != PAD_TOK) ? -extra[0] : 0.f;
    }
    __syncthreads();
}

// ---------------- deferred finishes ----------------
__global__ __launch_bounds__(512) void k_fin_all(
    int t0, const int* __restrict__ s,
    const float* __restrict__ lbBase, unsigned long long lbStride,
    const float* __restrict__ pmaxBase, unsigned long long pmaxStride,
    const float* __restrict__ spartAll, const float* __restrict__ bsw,
    float* __restrict__ nll, float* __restrict__ out)
{
    __shared__ float cv[512];
    __shared__ int   ci[512];
    __shared__ double sdd[512];
    __shared__ float extra[2];
    int idx = blockIdx.x >> 4;
    int tp = t0 + idx, b = blockIdx.x & 15;
    finish_step(tp, b, threadIdx.x, s,
                lbBase + (size_t)idx * lbStride,
                pmaxBase + (size_t)idx * pmaxStride,
                spartAll + (size_t)tp * 128,
                bsw, nll, out, cv, ci, sdd, extra);
}

// ---------------- per-step kernel 1: attention + hid (r11 verbatim, 16 blocks x 512) ----------------
__global__ __launch_bounds__(512) void k_attn(
    int t,
    const float* __restrict__ Whid, const float* __restrict__ bhid,
    const float* __restrict__ vw, const float* __restrict__ vb,
    const float* __restrict__ Wctx, const float* __restrict__ xwpre,
    const float* __restrict__ hs, float* __restrict__ hidg)
{
    int b = blockIdx.x, tid = threadIdx.x;
    __shared__ float hsh[HH], qs[HH], ctxs[HH];
    __shared__ float sc[AA], at[AA];
    const float* hp = hs + ((size_t)b*HSROW + (AA + t - 1))*HH;
    hsh[tid] = hp[tid];
    __syncthreads();
    {
        int j = tid;
        float acc = bhid[j];
        for (int k = 0; k < HH; k += 4) {
            float4 hv = *reinterpret_cast<const float4*>(&hsh[k]);
            acc = fmaf(hv.x, Whid[(k+0)*HH+j], acc);
            acc = fmaf(hv.y, Whid[(k+1)*HH+j], acc);
            acc = fmaf(hv.z, Whid[(k+2)*HH+j], acc);
            acc = fmaf(hv.w, Whid[(k+3)*HH+j], acc);
        }
        qs[j] = acc;
    }
    __syncthreads();
    {
        int w = tid >> 6, lane = tid & 63;
        for (int r = 0; r < 4; r++) {
            int a = w + 8*r;
            const float* mem = hs + ((size_t)b*HSROW + (t + a))*HH;
            float p = 0.f;
            for (int j = lane; j < HH; j += 64) p += tanhf(qs[j] + mem[j]) * vw[j];
            for (int m = 32; m >= 1; m >>= 1) p += __shfl_xor(p, m);
            if (lane == 0) sc[a] = (a >= AA - t) ? (p + vb[0]) : -1e20f;
        }
    }
    __syncthreads();
    if (tid < 64) {
        float v = (tid < 32) ? sc[tid] : -FLTMAX;
        float m = v;
        for (int sh = 16; sh >= 1; sh >>= 1) m = fmaxf(m, __shfl_xor(m, sh));
        float e = (tid < 32) ? __expf(v - m) : 0.f;
        float ss = e;
        for (int sh = 16; sh >= 1; sh >>= 1) ss += __shfl_xor(ss, sh);
        if (tid < 32) at[tid] = e / ss;
    }
    __syncthreads();
    {
        int j = tid;
        float ctx = 0.f;
        for (int a = 0; a < AA; a++)
            ctx += at[a] * hs[((size_t)b*HSROW + (t + a))*HH + j];
        ctxs[j] = ctx;
    }
    __syncthreads();
    {
        int j = tid;
        float acc = xwpre[((size_t)t*BB + b)*HH + j];
        const float* W2 = Wctx + (size_t)HH*HH;
        for (int k = 0; k < HH; k += 4) {
            float4 hv = *reinterpret_cast<const float4*>(&ctxs[k]);
            acc = fmaf(hv.x, W2[(k+0)*HH+j], acc);
            acc = fmaf(hv.y, W2[(k+1)*HH+j], acc);
            acc = fmaf(hv.z, W2[(k+2)*HH+j], acc);
            acc = fmaf(hv.w, W2[(k+3)*HH+j], acc);
        }
        const float scl = 1.0507009873554805f, al = 1.6732632423543772f;
        hidg[b*HH + j] = (acc > 0.f) ? scl*acc : scl*al*expm1f(acc);
    }
}

// ---------------- per-step kernel 2: gates (r11 verbatim, 128 blocks x 256) ----------------
__global__ __launch_bounds__(256) void k_gates(
    int t, const int* __restrict__ parents,
    const float4* __restrict__ WihT, const float4* __restrict__ WhhT,
    const float* __restrict__ blstm, const float* __restrict__ wsw,
    const float* __restrict__ hidg, float* __restrict__ hs,
    float* __restrict__ cvec, float* __restrict__ spart,
    float* __restrict__ zbuf)
{
    int bid = blockIdx.x, b = bid >> 3, hc = bid & 7, h0 = hc*64;
    int tid = threadIdx.x, g = tid >> 6, jj = tid & 63, j = h0 + jj, col = g*HH + j;
    __shared__ float hid_s[HH], h_s[HH];
    __shared__ float gsl[4][64];
    const float* hp = hs + ((size_t)b*HSROW + (AA + t - 1))*HH;
    for (int k = tid; k < HH; k += 256) { hid_s[k] = hidg[b*HH + k]; h_s[k] = hp[k]; }
    __syncthreads();
    float acc = blstm[col];
    #pragma unroll 8
    for (int kg = 0; kg < 128; kg++) {
        float4 w = WihT[(size_t)kg*2048 + col];
        float4 hv = *reinterpret_cast<const float4*>(&hid_s[kg*4]);
        acc = fmaf(hv.x, w.x, acc);
        acc = fmaf(hv.y, w.y, acc);
        acc = fmaf(hv.z, w.z, acc);
        acc = fmaf(hv.w, w.w, acc);
    }
    #pragma unroll 8
    for (int kg = 0; kg < 128; kg++) {
        float4 w = WhhT[(size_t)kg*2048 + col];
        float4 hv = *reinterpret_cast<const float4*>(&h_s[kg*4]);
        acc = fmaf(hv.x, w.x, acc);
        acc = fmaf(hv.y, w.y, acc);
        acc = fmaf(hv.z, w.z, acc);
        acc = fmaf(hv.w, w.w, acc);
    }
    gsl[g][jj] = acc;
    __syncthreads();
    if (tid >= 64 && tid < 128) {
        int jj2 = tid - 64;
        int par = parents[t];
        int tm1 = (t - 1 > 0) ? (t - 1) : 0;
        int p = (par < 0) ? 0 : ((par > tm1) ? tm1 : par);
        float v = (t == 0) ? 0.f : hs[((size_t)b*HSROW + (AA + p))*HH + h0 + jj2];
        zbuf[(size_t)b*ZK + 2*HH + h0 + jj2] = v;
    }
    if (tid < 64) {
        float gi = gsl[0][jj], gf = gsl[1][jj], gg = gsl[2][jj], go = gsl[3][jj];
        float cp = cvec[b*HH + j];
        float cn = sigm(gf)*cp + sigm(gi)*tanhf(gg);
        float hn = sigm(go)*tanhf(cn);
        cvec[b*HH + j] = cn;
        hs[((size_t)b*HSROW + (AA + t))*HH + j] = hn;
        zbuf[(size_t)b*ZK + j] = hn;
        zbuf[(size_t)b*ZK + HH + j] = cn;
        float sp = hn*wsw[j] + cn*wsw[HH + j];
        for (int m = 32; m >= 1; m >>= 1) sp += __shfl_xor(sp, m);
        if (jj == 0) spart[b*8 + hc] = sp;
    }
}

// ---------------- logits GEMM body v6: r15 body + DOUBLE-BUFFERED LDS staging ----------------
// Lane layout and ALL arithmetic chains verbatim r15 (kc asc, sub asc, kl asc, z.x..z.w
// nesting; shfl_xor(32) accA+accB combine; plain lb stores) -> bit-identical values.
// Only staging schedule changes: stage sub-chunk sc+1 into buffer B while computing from A,
// one barrier per sub-chunk.
template<int NT>
__device__ __forceinline__ void logits_body6(int chunk, int base_t,
    const float4* __restrict__ Wt4b, const float* __restrict__ bg,
    const float* __restrict__ zBase, size_t zStride,
    float* __restrict__ lbBase, size_t lbStride,
    float* __restrict__ pmaxBase, size_t pmaxStride,
    float* zs)   // 2 * NT*16*2*64 floats
{
    int tid = threadIdx.x;
    int lane = tid & 63;
    int cg = lane & 31;
    int kh = lane >> 5;
    int b0 = (tid >> 6) * 4;
    const int BUF = NT*16*2*64;

    const float4* wt0 = Wt4b + (size_t)(chunk*2 + 0)*(384*64) + cg;
    const float4* wt1 = Wt4b + (size_t)(chunk*2 + 0)*(384*64) + cg + 32;
    const float4* wt2 = Wt4b + (size_t)(chunk*2 + 1)*(384*64) + cg;
    const float4* wt3 = Wt4b + (size_t)(chunk*2 + 1)*(384*64) + cg + 32;

    float acc[NT][4][4];
    #pragma unroll
    for (int tt = 0; tt < NT; tt++)
        #pragma unroll
        for (int cc = 0; cc < 4; cc++) {
            float binit = (kh == 0) ? bg[chunk*CHW + cg + 32*cc] : 0.f;
            #pragma unroll
            for (int u = 0; u < 4; u++) acc[tt][cc][u] = binit;
        }

    const int NF4 = NT*16*2*16;          // float4 slots per sub-chunk
    auto STAGE = [&](int sc, float* dst) {
        int kc = sc >> 2, sub = sc & 3;
        #pragma unroll
        for (int p = 0; p < NF4/256; p++) {
            int fi = tid + p*256;
            int kl4 = fi & 15, khs = (fi >> 4) & 1, uu = (fi >> 5) & 15, tt = fi >> 9;
            const float* src = zBase + (size_t)(base_t + tt)*zStride + kc*512
                             + (size_t)uu*ZK + khs*256 + sub*64 + kl4*4;
            *reinterpret_cast<float4*>(&dst[(((tt*16 + uu)*2 + khs)*64) + kl4*4]) =
                *reinterpret_cast<const float4*>(src);
        }
    };

    STAGE(0, zs);
    __syncthreads();
    for (int sc = 0; sc < 12; sc++) {
        float* cur = zs + (sc & 1)*BUF;
        if (sc + 1 < 12) STAGE(sc + 1, zs + ((sc + 1) & 1)*BUF);
        int kc = sc >> 2, sub = sc & 3;
        int kgb = kc*128 + kh*64 + sub*16;
        const float4* w0P = wt0 + (size_t)kgb*64;
        const float4* w1P = wt1 + (size_t)kgb*64;
        const float4* w2P = wt2 + (size_t)kgb*64;
        const float4* w3P = wt3 + (size_t)kgb*64;
        #pragma unroll 4
        for (int kl = 0; kl < 16; kl++) {
            float4 w0 = w0P[kl*64];
            float4 w1 = w1P[kl*64];
            float4 w2 = w2P[kl*64];
            float4 w3 = w3P[kl*64];
            #pragma unroll
            for (int tt = 0; tt < NT; tt++) {
                #pragma unroll
                for (int u = 0; u < 4; u++) {
                    float4 z = *reinterpret_cast<const float4*>(
                        &cur[(((tt*16 + (b0 + u))*2 + kh)*64) + kl*4]);
                    acc[tt][0][u] = fmaf(z.x, w0.x, fmaf(z.y, w0.y, fmaf(z.z, w0.z, fmaf(z.w, w0.w, acc[tt][0][u]))));
                    acc[tt][1][u] = fmaf(z.x, w1.x, fmaf(z.y, w1.y, fmaf(z.z, w1.z, fmaf(z.w, w1.w, acc[tt][1][u]))));
                    acc[tt][2][u] = fmaf(z.x, w2.x, fmaf(z.y, w2.y, fmaf(z.z, w2.z, fmaf(z.w, w2.w, acc[tt][2][u]))));
                    acc[tt][3][u] = fmaf(z.x, w3.x, fmaf(z.y, w3.y, fmaf(z.z, w3.z, fmaf(z.w, w3.w, acc[tt][3][u]))));
                }
            }
        }
        __syncthreads();   // buffer B fully written + buffer A fully read
    }

    #pragma unroll
    for (int tt = 0; tt < NT; tt++) {
        float* lb   = lbBase   + (size_t)(base_t + tt)*lbStride;
        float* pmax = pmaxBase + (size_t)(base_t + tt)*pmaxStride;
        #pragma unroll
        for (int u = 0; u < 4; u++) {
            float vmax = -FLTMAX;
            #pragma unroll
            for (int cc = 0; cc < 4; cc++) {
                float a = acc[tt][cc][u];
                float oth = __shfl_xor(a, 32);
                float tot = a + oth;          // accA+accB (identical bits both halves)
                if (kh == 0) lb[(size_t)(b0 + u)*VV + chunk*CHW + cg + 32*cc] = tot;
                vmax = fmaxf(vmax, tot);
            }
            for (int m = 16; m >= 1; m >>= 1) vmax = fmaxf(vmax, __shfl_xor(vmax, m));
            if (lane == 0) pmax[chunk*BB + b0 + u] = vmax;
        }
    }
}

// mega: grid (21, 250)
__global__ __launch_bounds__(256) void k_logits_mega3(
    const float4* __restrict__ Wt4b, const float* __restrict__ bg,
    const float* __restrict__ zBase,
    float* __restrict__ lbBase, float* __restrict__ pmaxBase)
{
    __shared__ float zs[2*TGRP*16*2*64];
    logits_body6<TGRP>(blockIdx.y, blockIdx.x * TGRP, Wt4b, bg,
                       zBase, (size_t)BB*ZK, lbBase, 512000, pmaxBase, 4000, zs);
}

// per-step fallback (transposed): grid (250)
__global__ __launch_bounds__(256) void k_logits_T1(
    const float4* __restrict__ Wt4b, const float* __restrict__ bg,
    const float* __restrict__ zbuf,
    float* __restrict__ lb, float* __restrict__ pmax)
{
    __shared__ float zs[2*1*16*2*64];
    logits_body6<1>(blockIdx.x, 0, Wt4b, bg, zbuf, 0, lb, 0, pmax, 0, zs);
}

// ---------------- fallback untransposed logits (mode 0), grid (250) ----------------
__global__ __launch_bounds__(256) void k_logits_F(
    const float* __restrict__ Wg, const float* __restrict__ bg,
    const float* __restrict__ zbuf,
    float* __restrict__ lb, float* __restrict__ pmax)
{
    int tid = threadIdx.x;
    int chunk = blockIdx.x;
    int lane = tid & 63;
    int cg = lane & 31;
    int kh = lane >> 5;
    int b0 = (tid >> 6) * 4;

    float acc[4][4];
    #pragma unroll
    for (int cc = 0; cc < 4; cc++) {
        float binit = (kh == 0) ? bg[chunk*CHW + cg + 32*cc] : 0.f;
        #pragma unroll
        for (int u = 0; u < 4; u++) acc[cc][u] = binit;
    }

    for (int kc = 0; kc < 3; kc++) {
        const float* zb = zbuf + kc*512 + (size_t)b0*ZK;
        #pragma unroll 2
        for (int k4 = 0; k4 < 64; k4++) {
            int kb = kh*256 + k4*4;
            const float* wr = Wg + (size_t)(kc*512 + kb)*VV + chunk*CHW + cg;
            float4 w[4];
            #pragma unroll
            for (int cc = 0; cc < 4; cc++) {
                w[cc].x = wr[32*cc];
                w[cc].y = wr[(size_t)VV + 32*cc];
                w[cc].z = wr[(size_t)2*VV + 32*cc];
                w[cc].w = wr[(size_t)3*VV + 32*cc];
            }
            #pragma unroll
            for (int u = 0; u < 4; u++) {
                float4 z = *reinterpret_cast<const float4*>(&zb[(size_t)u*ZK + kb]);
                #pragma unroll
                for (int cc = 0; cc < 4; cc++)
                    acc[cc][u] = fmaf(z.x, w[cc].x, fmaf(z.y, w[cc].y, fmaf(z.z, w[cc].z, fmaf(z.w, w[cc].w, acc[cc][u]))));
            }
        }
    }

    #pragma unroll
    for (int u = 0; u < 4; u++) {
        float vmax = -FLTMAX;
        #pragma unroll
        for (int cc = 0; cc < 4; cc++) {
            float a = acc[cc][u];
            float oth = __shfl_xor(a, 32);
            float tot = a + oth;
            if (kh == 0) lb[(size_t)(b0 + u)*VV + chunk*CHW + cg + 32*cc] = tot;
            vmax = fmaxf(vmax, tot);
        }
        for (int m = 16; m >= 1; m >>= 1) vmax = fmaxf(vmax, __shfl_xor(vmax, m));
        if (lane == 0) pmax[chunk*BB + b0 + u] = vmax;
    }
}

// ---------------- loss ----------------
__global__ __launch_bounds__(256) void k_final_loss(
    const float* __restrict__ nll, float* __restrict__ out)
{
    __shared__ double cs2[256];
    int tid = threadIdx.x;
    double psm = 0.0;
    for (int i = tid; i < TT*BB; i += 256) psm += (double)nll[i];
    cs2[tid] = psm; __syncthreads();
    for (int sft = 128; sft >= 1; sft >>= 1) {
        if (tid < sft) cs2[tid] += cs2[tid+sft];
        __syncthreads();
    }
    if (tid == 0) out[0] = (float)(cs2[0] / (double)BB);
}

extern "C" void kernel_launch(void* const* d_in, const int* in_sizes, int n_in,
                              void* d_out, int out_size, void* d_ws, size_t ws_size,
                              hipStream_t stream)
{
    const int*   s_tok = (const int*)  d_in[0];
    const int*   par   = (const int*)  d_in[1];
    const float* emb   = (const float*)d_in[2];
    const float* Whid  = (const float*)d_in[3];
    const float* bhid  = (const float*)d_in[4];
    const float* vw    = (const float*)d_in[5];
    const float* vb    = (const float*)d_in[6];
    const float* Wctx  = (const float*)d_in[7];
    const float* bctx  = (const float*)d_in[8];
    const float* Wih   = (const float*)d_in[9];
    const float* Whh   = (const float*)d_in[10];
    const float* blstm = (const float*)d_in[11];
    const float* Wg    = (const float*)d_in[12];
    const float* bg    = (const float*)d_in[13];
    const float* wsw   = (const float*)d_in[14];
    const float* bsw   = (const float*)d_in[15];
    float* out = (float*)d_out;

    size_t ws_f = ws_size / sizeof(float);
    const size_t base_f = 786432 + 8192 + 516096 + 8192;       // hs,cvec,xwpre,hidg
    const size_t com_f  = 8064 + 1008 + 2*1048576;             // spartAll, nll, WihT, WhhT
    const size_t full_f = base_f + com_f + (size_t)63*4000 + (size_t)63*512000
                        + (size_t)63*24576 + 49152000;
    const size_t mid_f  = base_f + com_f + 4000 + 512000 + 24576 + 49152000;
    int mode = (ws_f >= full_f) ? 2 : ((ws_f >= mid_f) ? 1 : 0);

    float* ws = (float*)d_ws;
    size_t off = 0;
    float* hs      = ws + off; off += 786432;
    float* cvec    = ws + off; off += 8192;
    float* xwpre   = ws + off; off += 516096;
    float* hidg    = ws + off; off += 8192;
    float* pmaxAll = ws + off; off += (mode == 2) ? (size_t)63*4000 : 4000;
    float* spartAll= ws + off; off += 8064;
    float* nll     = ws + off; off += 1008;
    float* zbufAll = ws + off; off += (mode == 2) ? (size_t)63*24576 : 24576;
    float* lbAll   = ws + off; off += (mode == 2) ? (size_t)63*512000 : 512000;
    float4* WihT   = (float4*)(ws + off); off += 1048576;
    float4* WhhT   = (float4*)(ws + off); off += 1048576;
    float4* Wt4b   = (float4*)(ws + off); // only used in mode>=1

    hipMemsetAsync(hs, 0, (786432 + 8192) * sizeof(float), stream);

    hipLaunchKernelGGL(k_twl, dim3(1024), dim3(256), 0, stream, Wih, WihT);
    hipLaunchKernelGGL(k_twl, dim3(1024), dim3(256), 0, stream, Whh, WhhT);
    if (mode >= 1) {
        hipLaunchKernelGGL(k_tw, dim3(384*125), dim3(256), 0, stream, Wg, Wt4b);
    }
    hipLaunchKernelGGL(k_pre, dim3(TT*8), dim3(256), 0, stream, s_tok, emb, Wctx, bctx, xwpre);

    if (mode == 2) {
        // 1) recurrence: per-step attn + gates (r11 structure, weights L2-shared)
        for (int t = 0; t < TT; t++) {
            hipLaunchKernelGGL(k_attn, dim3(BB), dim3(512), 0, stream,
                t, Whid, bhid, vw, vb, Wctx, xwpre, hs, hidg);
            hipLaunchKernelGGL(k_gates, dim3(128), dim3(256), 0, stream,
                t, par, WihT, WhhT, blstm, wsw, hidg, hs, cvec,
                spartAll + (size_t)t*128, zbufAll + (size_t)t*BB*ZK);
        }
        // 2) all 63 logits GEMMs in one dispatch, z LDS-staged (double-buffered)
        hipLaunchKernelGGL(k_logits_mega3, dim3(NTG, NCHUNK), dim3(256), 0, stream,
            Wt4b, bg, zbufAll, lbAll, pmaxAll);
        // 3) all finishes
        hipLaunchKernelGGL(k_fin_all, dim3(TT*BB), dim3(512), 0, stream,
            0, s_tok, lbAll, (unsigned long long)512000,
            pmaxAll, (unsigned long long)4000,
            spartAll, bsw, nll, out);
    } else {
        for (int t = 0; t < TT; t++) {
            hipLaunchKernelGGL(k_attn, dim3(BB), dim3(512), 0, stream,
                t, Whid, bhid, vw, vb, Wctx, xwpre, hs, hidg);
            hipLaunchKernelGGL(k_gates, dim3(128), dim3(256), 0, stream,
                t, par, WihT, WhhT, blstm, wsw, hidg, hs, cvec,
                spartAll + (size_t)t*128, zbufAll);
            if (mode >= 1) {
                hipLaunchKernelGGL(k_logits_T1, dim3(NCHUNK), dim3(256), 0, stream,
                    Wt4b, bg, zbufAll, lbAll, pmaxAll);
            } else {
                hipLaunchKernelGGL(k_logits_F, dim3(NCHUNK), dim3(256), 0, stream,
                    Wg, bg, zbufAll, lbAll, pmaxAll);
            }
            hipLaunchKernelGGL(k_fin_all, dim3(BB), dim3(512), 0, stream,
                t, s_tok, lbAll, (unsigned long long)0, pmaxAll, (unsigned long long)0,
                spartAll, bsw, nll, out);
        }
    }
    hipLaunchKernelGGL(k_final_loss, dim3(1), dim3(256), 0, stream, nll, out);
}